// Round 1
// baseline (13023.795 us; speedup 1.0000x reference)
//
#include <hip/hip_runtime.h>

// SOSA forward (iSQRT-COV gate) — round 1: correct fp32 baseline.
// B=64, C=512(=M), H=W=28, d=784. NS iterations kept in fp32 vector ALU.
// Key algebraic simplifications (verified against reference math):
//  - sqrt(normA) scale cancels in min-max normalization -> dropped.
//  - final Y@Tf only needed via column means -> colmean(Y) @ Tf (vector-matrix).
//  - cov kernel epilogue fuses A = cov/normA and Z0 = 1.5I - 0.5A.

#define B_  64
#define C_  512
#define D_  784
#define MS_ ((size_t)D_ * D_)
#define BLK 64
#define KS  16

__global__ __launch_bounds__(64) void zero_kernel(float* __restrict__ p, int n) {
    int i = blockIdx.x * 64 + threadIdx.x;
    if (i < n) p[i] = 0.f;
}

// mu[b,i] = mean_c X[b,c,i];  ssq[b] += sum_{c,i} X^2  (atomic)
__global__ __launch_bounds__(256) void mu_kernel(const float* __restrict__ X,
                                                 float* __restrict__ mu,
                                                 float* __restrict__ ssq) {
    int b = blockIdx.y;
    int i = blockIdx.x * 256 + threadIdx.x;
    float s = 0.f, q = 0.f;
    if (i < D_) {
        const float* xb = X + (size_t)b * C_ * D_ + i;
        for (int c = 0; c < C_; ++c) { float v = xb[(size_t)c * D_]; s += v; q += v * v; }
        mu[b * D_ + i] = s * (1.f / C_);
    }
    __shared__ float red[256];
    red[threadIdx.x] = q;
    __syncthreads();
    for (int off = 128; off > 0; off >>= 1) {
        if (threadIdx.x < off) red[threadIdx.x] += red[threadIdx.x + off];
        __syncthreads();
    }
    if (threadIdx.x == 0) atomicAdd(&ssq[b], red[0]);
}

// rnorm[b] = 1 / (ssq[b]/M - sum_i mu^2)
__global__ __launch_bounds__(256) void trace_kernel(const float* __restrict__ mu,
                                                    const float* __restrict__ ssq,
                                                    float* __restrict__ rnorm) {
    int b = blockIdx.x;
    float q = 0.f;
    for (int i = threadIdx.x; i < D_; i += 256) { float m = mu[b * D_ + i]; q += m * m; }
    __shared__ float red[256];
    red[threadIdx.x] = q;
    __syncthreads();
    for (int off = 128; off > 0; off >>= 1) {
        if (threadIdx.x < off) red[threadIdx.x] += red[threadIdx.x + off];
        __syncthreads();
    }
    if (threadIdx.x == 0) {
        float tr = ssq[b] * (1.f / C_) - red[0];
        rnorm[b] = 1.f / tr;
    }
}

// A[bz] = ((1/M) X^T X - mu mu^T) * rnorm ;  Z[bz] = 1.5 I - 0.5 A
__global__ __launch_bounds__(256) void cov_kernel(const float* __restrict__ X,
                                                  const float* __restrict__ mu,
                                                  const float* __restrict__ rnorm,
                                                  float* __restrict__ Aout,
                                                  float* __restrict__ Zout, int b0) {
    int bz = blockIdx.z;
    int b  = b0 + bz;
    const float* Xb = X + (size_t)b * C_ * D_;
    float* Ab = Aout + (size_t)bz * MS_;
    float* Zb = Zout + (size_t)bz * MS_;
    __shared__ float Xi[KS][BLK];
    __shared__ float Xj[KS][BLK];
    int t  = threadIdx.x;
    int tx = t & 15, ty = t >> 4;
    int lr = t >> 6, lc = t & 63;
    int rowBase = blockIdx.y * BLK, colBase = blockIdx.x * BLK;
    float acc[4][4] = {};
    for (int k0 = 0; k0 < C_; k0 += KS) {
#pragma unroll
        for (int i2 = 0; i2 < 4; ++i2) {
            int kr = k0 + lr + 4 * i2;
            int ci = rowBase + lc;
            int cj = colBase + lc;
            Xi[lr + 4 * i2][lc] = (ci < D_) ? Xb[(size_t)kr * D_ + ci] : 0.f;
            Xj[lr + 4 * i2][lc] = (cj < D_) ? Xb[(size_t)kr * D_ + cj] : 0.f;
        }
        __syncthreads();
#pragma unroll
        for (int kk = 0; kk < KS; ++kk) {
            float a0 = Xi[kk][ty * 4 + 0], a1 = Xi[kk][ty * 4 + 1];
            float a2 = Xi[kk][ty * 4 + 2], a3 = Xi[kk][ty * 4 + 3];
            float b0v = Xj[kk][tx * 4 + 0], b1v = Xj[kk][tx * 4 + 1];
            float b2v = Xj[kk][tx * 4 + 2], b3v = Xj[kk][tx * 4 + 3];
            acc[0][0] += a0 * b0v; acc[0][1] += a0 * b1v; acc[0][2] += a0 * b2v; acc[0][3] += a0 * b3v;
            acc[1][0] += a1 * b0v; acc[1][1] += a1 * b1v; acc[1][2] += a1 * b2v; acc[1][3] += a1 * b3v;
            acc[2][0] += a2 * b0v; acc[2][1] += a2 * b1v; acc[2][2] += a2 * b2v; acc[2][3] += a2 * b3v;
            acc[3][0] += a3 * b0v; acc[3][1] += a3 * b1v; acc[3][2] += a3 * b2v; acc[3][3] += a3 * b3v;
        }
        __syncthreads();
    }
    float rn = rnorm[b];
#pragma unroll
    for (int i = 0; i < 4; ++i) {
        int r = rowBase + ty * 4 + i;
        if (r >= D_) continue;
        float mi = mu[b * D_ + r];
#pragma unroll
        for (int j = 0; j < 4; ++j) {
            int c = colBase + tx * 4 + j;
            if (c >= D_) continue;
            float mj = mu[b * D_ + c];
            float P  = acc[i][j] * (1.f / C_) - mi * mj;
            float Av = P * rn;
            Ab[(size_t)r * D_ + c] = Av;
            Zb[(size_t)r * D_ + c] = ((r == c) ? 1.5f : 0.f) - 0.5f * Av;
        }
    }
}

// C = A @ B   (EPI=0)   or   C = 1.5 I - 0.5 (A @ B)  (EPI=1); all 784x784, batched over z.
template <int EPI>
__global__ __launch_bounds__(256) void gemm_dd(const float* __restrict__ Ag,
                                               const float* __restrict__ Bg,
                                               float* __restrict__ Cg) {
    int bz = blockIdx.z;
    const float* A  = Ag + (size_t)bz * MS_;
    const float* Bm = Bg + (size_t)bz * MS_;
    float* Cm = Cg + (size_t)bz * MS_;
    __shared__ float As[KS][BLK + 4];   // transposed A tile; +4 pad: conflict-free writes, aligned b128 reads
    __shared__ float Bs[KS][BLK];
    int t  = threadIdx.x;
    int tx = t & 15, ty = t >> 4;
    int ar = t >> 4, ak = t & 15;   // A loader
    int bk = t >> 6, bc = t & 63;   // B loader
    int rowBase = blockIdx.y * BLK, colBase = blockIdx.x * BLK;
    float acc[4][4] = {};
    for (int k0 = 0; k0 < D_; k0 += KS) {
#pragma unroll
        for (int i2 = 0; i2 < 4; ++i2) {
            int r = rowBase + ar + 16 * i2;
            As[ak][ar + 16 * i2] = (r < D_) ? A[(size_t)r * D_ + k0 + ak] : 0.f;
        }
#pragma unroll
        for (int i2 = 0; i2 < 4; ++i2) {
            int c = colBase + bc;
            Bs[bk + 4 * i2][bc] = (c < D_) ? Bm[(size_t)(k0 + bk + 4 * i2) * D_ + c] : 0.f;
        }
        __syncthreads();
#pragma unroll
        for (int kk = 0; kk < KS; ++kk) {
            float a0 = As[kk][ty * 4 + 0], a1 = As[kk][ty * 4 + 1];
            float a2 = As[kk][ty * 4 + 2], a3 = As[kk][ty * 4 + 3];
            float b0v = Bs[kk][tx * 4 + 0], b1v = Bs[kk][tx * 4 + 1];
            float b2v = Bs[kk][tx * 4 + 2], b3v = Bs[kk][tx * 4 + 3];
            acc[0][0] += a0 * b0v; acc[0][1] += a0 * b1v; acc[0][2] += a0 * b2v; acc[0][3] += a0 * b3v;
            acc[1][0] += a1 * b0v; acc[1][1] += a1 * b1v; acc[1][2] += a1 * b2v; acc[1][3] += a1 * b3v;
            acc[2][0] += a2 * b0v; acc[2][1] += a2 * b1v; acc[2][2] += a2 * b2v; acc[2][3] += a2 * b3v;
            acc[3][0] += a3 * b0v; acc[3][1] += a3 * b1v; acc[3][2] += a3 * b2v; acc[3][3] += a3 * b3v;
        }
        __syncthreads();
    }
#pragma unroll
    for (int i = 0; i < 4; ++i) {
        int r = rowBase + ty * 4 + i;
        if (r >= D_) continue;
#pragma unroll
        for (int j = 0; j < 4; ++j) {
            int c = colBase + tx * 4 + j;
            if (c >= D_) continue;
            float v = acc[i][j];
            if (EPI == 1) v = ((r == c) ? 1.5f : 0.f) - 0.5f * v;
            Cm[(size_t)r * D_ + c] = v;
        }
    }
}

// u[b,k] = (1/d) sum_i Y[bz][i,k]
__global__ __launch_bounds__(256) void colmean_kernel(const float* __restrict__ Y,
                                                      float* __restrict__ u, int b0) {
    int bz = blockIdx.y;
    int k  = blockIdx.x * 256 + threadIdx.x;
    if (k >= D_) return;
    const float* Yb = Y + (size_t)bz * MS_;
    float s = 0.f;
    for (int i = 0; i < D_; ++i) s += Yb[(size_t)i * D_ + k];
    u[(size_t)(b0 + bz) * D_ + k] = s * (1.f / D_);
}

// s[b,j] = sum_k u[b,k] * T[bz][k,j]
__global__ __launch_bounds__(256) void srow_kernel(const float* __restrict__ T,
                                                   const float* __restrict__ u,
                                                   float* __restrict__ s, int b0) {
    int bz = blockIdx.y;
    int j  = blockIdx.x * 256 + threadIdx.x;
    if (j >= D_) return;
    const float* Tb = T + (size_t)bz * MS_;
    const float* ub = u + (size_t)(b0 + bz) * D_;
    float acc = 0.f;
    for (int k = 0; k < D_; ++k) acc += ub[k] * Tb[(size_t)k * D_ + j];
    s[(size_t)(b0 + bz) * D_ + j] = acc;
}

// ycov[b,:] = (s - min) / (max - min)
__global__ __launch_bounds__(256) void minmax_kernel(const float* __restrict__ s,
                                                     float* __restrict__ ycov, int b0) {
    int b = b0 + blockIdx.x;
    const float* sb = s + (size_t)b * D_;
    float mn = 1e30f, mx = -1e30f;
    for (int i = threadIdx.x; i < D_; i += 256) {
        float v = sb[i];
        mn = fminf(mn, v);
        mx = fmaxf(mx, v);
    }
    __shared__ float rmn[256], rmx[256];
    rmn[threadIdx.x] = mn;
    rmx[threadIdx.x] = mx;
    __syncthreads();
    for (int off = 128; off > 0; off >>= 1) {
        if (threadIdx.x < off) {
            rmn[threadIdx.x] = fminf(rmn[threadIdx.x], rmn[threadIdx.x + off]);
            rmx[threadIdx.x] = fmaxf(rmx[threadIdx.x], rmx[threadIdx.x + off]);
        }
        __syncthreads();
    }
    float gmn = rmn[0], gmx = rmx[0];
    float inv = 1.f / (gmx - gmn);
    for (int i = threadIdx.x; i < D_; i += 256)
        ycov[(size_t)b * D_ + i] = (sb[i] - gmn) * inv;
}

// out[b,c,i] = ycov[b,i] * X[b,c,i]   (float4 vectorized; D%4==0 so lanes stay in-row)
__global__ __launch_bounds__(256) void scale_kernel(const float* __restrict__ X,
                                                    const float* __restrict__ ycov,
                                                    float* __restrict__ out) {
    size_t idx = (size_t)blockIdx.x * 256 + threadIdx.x;
    size_t n   = idx * 4;
    if (n >= (size_t)B_ * C_ * D_) return;
    int b = (int)(n / ((size_t)C_ * D_));
    int i = (int)(n % D_);
    float4 x4 = *(const float4*)(X + n);
    float4 y4 = *(const float4*)(ycov + (size_t)b * D_ + i);
    float4 o;
    o.x = x4.x * y4.x; o.y = x4.y * y4.y; o.z = x4.z * y4.z; o.w = x4.w * y4.w;
    *(float4*)(out + n) = o;
}

extern "C" void kernel_launch(void* const* d_in, const int* in_sizes, int n_in,
                              void* d_out, int out_size, void* d_ws, size_t ws_size,
                              hipStream_t stream) {
    const float* X = (const float*)d_in[0];
    float* out = (float*)d_out;
    float* ws  = (float*)d_ws;

    // header layout
    float* mu    = ws;                    // B*D
    float* ssq   = mu + (size_t)B_ * D_;  // B
    float* rnorm = ssq + B_;              // B
    float* uvec  = rnorm + B_;            // B*D
    float* svec  = uvec + (size_t)B_ * D_;
    float* ycov  = svec + (size_t)B_ * D_;
    size_t header = (size_t)((ycov + (size_t)B_ * D_) - ws);
    header = (header + 63) & ~(size_t)63;
    float* mats = ws + header;

    size_t availf = (ws_size / 4 > header) ? (ws_size / 4 - header) : 0;
    int NB = (int)(availf / (5 * MS_));
    if (NB < 1) NB = 1;
    if (NB > B_) NB = B_;

    zero_kernel<<<1, 64, 0, stream>>>(ssq, B_);
    mu_kernel<<<dim3((D_ + 255) / 256, B_), 256, 0, stream>>>(X, mu, ssq);
    trace_kernel<<<B_, 256, 0, stream>>>(mu, ssq, rnorm);

    const int NT = (D_ + BLK - 1) / BLK;  // 13
    for (int b0 = 0; b0 < B_; b0 += NB) {
        int bc = B_ - b0 < NB ? B_ - b0 : NB;
        float* bT = mats;
        float* bY[2] = { mats + (size_t)NB * MS_, mats + 2 * (size_t)NB * MS_ };
        float* bZ[2] = { mats + 3 * (size_t)NB * MS_, mats + 4 * (size_t)NB * MS_ };
        dim3 grid(NT, NT, bc);

        cov_kernel<<<grid, 256, 0, stream>>>(X, mu, rnorm, bT, bZ[0], b0);
        gemm_dd<0><<<grid, 256, 0, stream>>>(bT, bZ[0], bY[0]);   // Y0 = A @ T0
        int cy = 0, cz = 0;
        for (int it = 0; it < 3; ++it) {
            gemm_dd<1><<<grid, 256, 0, stream>>>(bZ[cz], bY[cy], bT);      // T = 1.5I - 0.5 Z@Y
            gemm_dd<0><<<grid, 256, 0, stream>>>(bY[cy], bT, bY[cy ^ 1]);  // Y' = Y@T
            gemm_dd<0><<<grid, 256, 0, stream>>>(bT, bZ[cz], bZ[cz ^ 1]);  // Z' = T@Z
            cy ^= 1; cz ^= 1;
        }
        gemm_dd<1><<<grid, 256, 0, stream>>>(bZ[cz], bY[cy], bT);          // Tf
        colmean_kernel<<<dim3(4, bc), 256, 0, stream>>>(bY[cy], uvec, b0);
        srow_kernel<<<dim3(4, bc), 256, 0, stream>>>(bT, uvec, svec, b0);
        minmax_kernel<<<bc, 256, 0, stream>>>(svec, ycov, b0);
    }

    size_t n4 = ((size_t)B_ * C_ * D_) / 4;
    scale_kernel<<<(unsigned)((n4 + 255) / 256), 256, 0, stream>>>(X, ycov, out);
}

// Round 2
// 3964.394 us; speedup vs baseline: 3.2852x; 3.2852x over previous
//
#include <hip/hip_runtime.h>

// SOSA forward — round 2: Gram-domain Newton-Schulz + split-3 bf16 MFMA.
// A = W^T W (W = Xc/||Xc||_F, 512x784). All NS iterates are polynomials in A:
//   Y_k = W^T y_k W,  Z_k = c_k I + W^T z_k W,  c_k = 1.5^(k+1).
// Per iteration (512^3 products): u=G@y, m=z@u (epi: t=-0.5(cy+m)), v=G@t,
//   y'=1.5y+y@v, z'=1.5z+ct+v@z.   Final: u,m->tf, v, yf (row-only).
// Gate: s = a^T yf W (a = W 1/d), minmax-normalized (sqrt(normA) cancels).
// Precision: split-3 bf16 (C = Ah@Bh + Ah@Bl + Al@Bh, fp32 MFMA accum),
// exact transposed copies stored from epilogue via per-wave LDS transpose.

typedef unsigned short u16;
typedef unsigned int u32;
typedef short bf16x8 __attribute__((ext_vector_type(8)));
typedef float f32x4 __attribute__((ext_vector_type(4)));

#define B_  64
#define C_  512                 // channels == Gram dimension
#define D_  784
#define DP_ 800                 // padded spatial (K for SYRK)
#define NN_ ((size_t)C_ * C_)   // 262144
#define WN_ ((size_t)C_ * DP_)  // 409600

__device__ inline u16 f2bf(float f) {
    u32 u = __builtin_bit_cast(u32, f);
    u += 0x7fffu + ((u >> 16) & 1u);
    return (u16)(u >> 16);
}
__device__ inline float bf2f(u16 h) {
    u32 u = ((u32)h) << 16;
    return __builtin_bit_cast(float, u);
}

// ---------------------------------------------------------------- small ops
__global__ __launch_bounds__(64) void zero_kernel(float* __restrict__ p, int n) {
    int i = blockIdx.x * 64 + threadIdx.x;
    if (i < n) p[i] = 0.f;
}

// mu[b,i] = mean_c X[b,c,i];  ssq[b] += sum X^2
__global__ __launch_bounds__(256) void mu_kernel(const float* __restrict__ X,
                                                 float* __restrict__ mu,
                                                 float* __restrict__ ssq) {
    int b = blockIdx.y;
    int i = blockIdx.x * 256 + threadIdx.x;
    float s = 0.f, q = 0.f;
    if (i < D_) {
        const float* xb = X + (size_t)b * C_ * D_ + i;
        for (int c = 0; c < C_; ++c) { float v = xb[(size_t)c * D_]; s += v; q += v * v; }
        mu[b * D_ + i] = s * (1.f / C_);
    }
    __shared__ float red[256];
    red[threadIdx.x] = q;
    __syncthreads();
    for (int off = 128; off > 0; off >>= 1) {
        if (threadIdx.x < off) red[threadIdx.x] += red[threadIdx.x + off];
        __syncthreads();
    }
    if (threadIdx.x == 0) atomicAdd(&ssq[b], red[0]);
}

// rfro[b] = 1/||Xc||_F = rsqrt(ssq - C*sum(mu^2))
__global__ __launch_bounds__(256) void rfro_kernel(const float* __restrict__ mu,
                                                   const float* __restrict__ ssq,
                                                   float* __restrict__ rfro) {
    int b = blockIdx.x;
    float q = 0.f;
    for (int i = threadIdx.x; i < D_; i += 256) { float m = mu[b * D_ + i]; q += m * m; }
    __shared__ float red[256];
    red[threadIdx.x] = q;
    __syncthreads();
    for (int off = 128; off > 0; off >>= 1) {
        if (threadIdx.x < off) red[threadIdx.x] += red[threadIdx.x + off];
        __syncthreads();
    }
    if (threadIdx.x == 0) rfro[b] = rsqrtf(ssq[b] - (float)C_ * red[0]);
}

// W = (X - mu) * rfro, split hi/lo bf16, cols 784..799 zero-padded.
__global__ __launch_bounds__(256) void wbuild_kernel(const float* __restrict__ X,
                                                     const float* __restrict__ mu,
                                                     const float* __restrict__ rfro,
                                                     u16* __restrict__ Wh, u16* __restrict__ Wl,
                                                     int b0, int bc) {
    size_t idx = (size_t)blockIdx.x * 256 + threadIdx.x;
    size_t total = (size_t)bc * C_ * (DP_ / 8);
    if (idx >= total) return;
    int ch = (int)(idx % (DP_ / 8));
    size_t rest = idx / (DP_ / 8);
    int c = (int)(rest % C_);
    int bz = (int)(rest / C_);
    int b = b0 + bz;
    int i0 = ch * 8;
    u32 hw[4] = {0, 0, 0, 0}, lw[4] = {0, 0, 0, 0};
    if (i0 < D_) {   // D_=784 = 98*8 -> chunks are full or all-pad
        float rf = rfro[b];
        const float* xr = X + ((size_t)b * C_ + c) * D_ + i0;
        const float* mr = mu + (size_t)b * D_ + i0;
#pragma unroll
        for (int e2 = 0; e2 < 4; ++e2) {
            float v0 = (xr[2 * e2] - mr[2 * e2]) * rf;
            float v1 = (xr[2 * e2 + 1] - mr[2 * e2 + 1]) * rf;
            u16 h0 = f2bf(v0), h1 = f2bf(v1);
            u16 l0 = f2bf(v0 - bf2f(h0)), l1 = f2bf(v1 - bf2f(h1));
            hw[e2] = (u32)h0 | ((u32)h1 << 16);
            lw[e2] = (u32)l0 | ((u32)l1 << 16);
        }
    }
    size_t o = ((size_t)bz * C_ + c) * DP_ + i0;
    uint4 ph; ph.x = hw[0]; ph.y = hw[1]; ph.z = hw[2]; ph.w = hw[3];
    uint4 pl; pl.x = lw[0]; pl.y = lw[1]; pl.z = lw[2]; pl.w = lw[3];
    *(uint4*)&Wh[o] = ph;
    *(uint4*)&Wl[o] = pl;
}

// z0 = -0.5 I (all four arrays of slot 0)
__global__ __launch_bounds__(256) void z0init_kernel(u16* __restrict__ zh, u16* __restrict__ zl,
                                                     u16* __restrict__ zth, u16* __restrict__ ztl,
                                                     int bc) {
    size_t idx = (size_t)blockIdx.x * 256 + threadIdx.x;
    if (idx >= (size_t)bc * NN_) return;
    int r = (int)((idx >> 9) & 511);
    int c = (int)(idx & 511);
    u16 h = (r == c) ? (u16)0xBF00 : (u16)0;   // bf16(-0.5)
    zh[idx] = h; zl[idx] = 0; zth[idx] = h; ztl[idx] = 0;
}

// avec[b,c] = (1/d) sum_i W[c,i]
__global__ __launch_bounds__(128) void arowsum_kernel(const u16* __restrict__ Wh,
                                                      const u16* __restrict__ Wl,
                                                      float* __restrict__ avec, int b0) {
    int c = blockIdx.x, bz = blockIdx.y;
    const u16* wh = Wh + ((size_t)bz * C_ + c) * DP_;
    const u16* wl = Wl + ((size_t)bz * C_ + c) * DP_;
    float s = 0.f;
    for (int i = threadIdx.x; i < DP_; i += 128) s += bf2f(wh[i]) + bf2f(wl[i]);
    __shared__ float red[128];
    red[threadIdx.x] = s;
    __syncthreads();
    for (int off = 64; off > 0; off >>= 1) {
        if (threadIdx.x < off) red[threadIdx.x] += red[threadIdx.x + off];
        __syncthreads();
    }
    if (threadIdx.x == 0) avec[(size_t)(b0 + blockIdx.y) * C_ + c] = red[0] * (1.f / D_);
}

// w2[b,j] = sum_c avec[b,c] * yf[c,j]
__global__ __launch_bounds__(256) void w2_kernel(const u16* __restrict__ yfh,
                                                 const u16* __restrict__ yfl,
                                                 const float* __restrict__ avec,
                                                 float* __restrict__ w2, int b0) {
    int bz = blockIdx.y;
    int j = blockIdx.x * 256 + threadIdx.x;
    const u16* yh = yfh + (size_t)bz * NN_;
    const u16* yl = yfl + (size_t)bz * NN_;
    const float* a = avec + (size_t)(b0 + bz) * C_;
    float s = 0.f;
    for (int c = 0; c < C_; ++c) s += a[c] * (bf2f(yh[(size_t)c * C_ + j]) + bf2f(yl[(size_t)c * C_ + j]));
    w2[(size_t)(b0 + bz) * C_ + j] = s;
}

// svec[b,j] = sum_c w2[b,c] * W[c,j]   (j < 784)
__global__ __launch_bounds__(256) void svec_kernel(const float* __restrict__ w2,
                                                   const u16* __restrict__ Wh,
                                                   const u16* __restrict__ Wl,
                                                   float* __restrict__ svec, int b0) {
    int bz = blockIdx.y;
    int j = blockIdx.x * 256 + threadIdx.x;
    if (j >= D_) return;
    const u16* wh = Wh + (size_t)bz * WN_;
    const u16* wl = Wl + (size_t)bz * WN_;
    const float* w = w2 + (size_t)(b0 + bz) * C_;
    float s = 0.f;
    for (int c = 0; c < C_; ++c) s += w[c] * (bf2f(wh[(size_t)c * DP_ + j]) + bf2f(wl[(size_t)c * DP_ + j]));
    svec[(size_t)(b0 + bz) * D_ + j] = s;
}

__global__ __launch_bounds__(256) void minmax_kernel(const float* __restrict__ s,
                                                     float* __restrict__ ycov, int b0) {
    int b = b0 + blockIdx.x;
    const float* sb = s + (size_t)b * D_;
    float mn = 1e30f, mx = -1e30f;
    for (int i = threadIdx.x; i < D_; i += 256) {
        float v = sb[i];
        mn = fminf(mn, v);
        mx = fmaxf(mx, v);
    }
    __shared__ float rmn[256], rmx[256];
    rmn[threadIdx.x] = mn;
    rmx[threadIdx.x] = mx;
    __syncthreads();
    for (int off = 128; off > 0; off >>= 1) {
        if (threadIdx.x < off) {
            rmn[threadIdx.x] = fminf(rmn[threadIdx.x], rmn[threadIdx.x + off]);
            rmx[threadIdx.x] = fmaxf(rmx[threadIdx.x], rmx[threadIdx.x + off]);
        }
        __syncthreads();
    }
    float gmn = rmn[0], gmx = rmx[0];
    float inv = 1.f / (gmx - gmn);
    for (int i = threadIdx.x; i < D_; i += 256)
        ycov[(size_t)b * D_ + i] = (sb[i] - gmn) * inv;
}

__global__ __launch_bounds__(256) void scale_kernel(const float* __restrict__ X,
                                                    const float* __restrict__ ycov,
                                                    float* __restrict__ out) {
    size_t idx = (size_t)blockIdx.x * 256 + threadIdx.x;
    size_t n = idx * 4;
    if (n >= (size_t)B_ * C_ * D_) return;
    int b = (int)(n / ((size_t)C_ * D_));
    int i = (int)(n % D_);
    float4 x4 = *(const float4*)(X + n);
    float4 y4 = *(const float4*)(ycov + (size_t)b * D_ + i);
    float4 o;
    o.x = x4.x * y4.x; o.y = x4.y * y4.y; o.z = x4.z * y4.z; o.w = x4.w * y4.w;
    *(float4*)(out + n) = o;
}

// ---------------------------------------------------------------- MFMA GEMM
// C(512x512) = A @ B with BT-array holding B^T row-major; split-3 bf16.
// Epilogue: val = alpha*P + diagv*(r==c) + beta*E1 + gamma*E2; O1 row + transposed
// (via per-wave LDS transpose); optional second output O2 = alpha2*P + diag2*(r==c).
__global__ __launch_bounds__(256) void gemm_ns(
    const u16* __restrict__ Ah, const u16* __restrict__ Al,
    const u16* __restrict__ Bh, const u16* __restrict__ Bl,
    int K, int lda, size_t strideA, size_t strideB,
    float alpha, float diagv,
    const u16* __restrict__ E1h, const u16* __restrict__ E1l, float beta,
    const u16* __restrict__ E2h, const u16* __restrict__ E2l, float gamma,
    u16* __restrict__ O1h, u16* __restrict__ O1l,
    u16* __restrict__ O1th, u16* __restrict__ O1tl,
    float alpha2, float diag2,
    u16* __restrict__ O2h, u16* __restrict__ O2l)
{
    __shared__ u16 lds[4][128][40];   // Ah,Al,BTh,BTl tiles; +8 pad -> 2-way banks only
    int bz = blockIdx.z;
    int t = threadIdx.x;
    int lane = t & 63, wid = t >> 6;
    int wr = wid >> 1, wc = wid & 1;
    int row0 = blockIdx.y * 128, col0 = blockIdx.x * 128;
    const u16* sA[2] = { Ah + (size_t)bz * strideA, Al + (size_t)bz * strideA };
    const u16* sB[2] = { Bh + (size_t)bz * strideB, Bl + (size_t)bz * strideB };
    int lr = t >> 2, lch = (t & 3) * 8;   // loader: rows lr, lr+64; 8-elem chunk
    f32x4 acc[4][4] = {};

    for (int k0 = 0; k0 < K; k0 += 32) {
        __syncthreads();
#pragma unroll
        for (int s = 0; s < 2; ++s) {
            uint4 va0 = *(const uint4*)&sA[s][(size_t)(row0 + lr) * lda + k0 + lch];
            uint4 va1 = *(const uint4*)&sA[s][(size_t)(row0 + lr + 64) * lda + k0 + lch];
            uint4 vb0 = *(const uint4*)&sB[s][(size_t)(col0 + lr) * lda + k0 + lch];
            uint4 vb1 = *(const uint4*)&sB[s][(size_t)(col0 + lr + 64) * lda + k0 + lch];
            *(uint4*)&lds[s][lr][lch] = va0;
            *(uint4*)&lds[s][lr + 64][lch] = va1;
            *(uint4*)&lds[2 + s][lr][lch] = vb0;
            *(uint4*)&lds[2 + s][lr + 64][lch] = vb1;
        }
        __syncthreads();
        int koff = (lane >> 4) * 8;
        bf16x8 bhf[4], blf[4];
#pragma unroll
        for (int n = 0; n < 4; ++n) {
            int rB = wc * 64 + n * 16 + (lane & 15);
            bhf[n] = *(const bf16x8*)&lds[2][rB][koff];
            blf[n] = *(const bf16x8*)&lds[3][rB][koff];
        }
#pragma unroll
        for (int m = 0; m < 4; ++m) {
            int rA = wr * 64 + m * 16 + (lane & 15);
            bf16x8 ah = *(const bf16x8*)&lds[0][rA][koff];
            bf16x8 al = *(const bf16x8*)&lds[1][rA][koff];
#pragma unroll
            for (int n = 0; n < 4; ++n) {
                acc[m][n] = __builtin_amdgcn_mfma_f32_16x16x32_bf16(ah, bhf[n], acc[m][n], 0, 0, 0);
                acc[m][n] = __builtin_amdgcn_mfma_f32_16x16x32_bf16(ah, blf[n], acc[m][n], 0, 0, 0);
                acc[m][n] = __builtin_amdgcn_mfma_f32_16x16x32_bf16(al, bhf[n], acc[m][n], 0, 0, 0);
            }
        }
    }
    __syncthreads();   // staging LDS now reusable as transpose scratch

    float* scr = ((float*)&lds[0][0][0]) + (size_t)wid * (32 * 68);
    int r0g = row0 + wr * 64, c0g = col0 + wc * 64;
    size_t eoff = (size_t)bz * NN_;
    const u16* e1h = E1h ? E1h + eoff : (const u16*)0;
    const u16* e1l = E1l ? E1l + eoff : (const u16*)0;
    const u16* e2h = E2h ? E2h + eoff : (const u16*)0;
    const u16* e2l = E2l ? E2l + eoff : (const u16*)0;
    u16* o1h = O1h ? O1h + eoff : (u16*)0;
    u16* o1l = O1l ? O1l + eoff : (u16*)0;
    u16* o2h = O2h ? O2h + eoff : (u16*)0;
    u16* o2l = O2l ? O2l + eoff : (u16*)0;

#pragma unroll
    for (int p = 0; p < 2; ++p) {
#pragma unroll
        for (int a2 = 0; a2 < 2; ++a2) {
            int ai = 2 * p + a2;
#pragma unroll
            for (int n = 0; n < 4; ++n) {
                int cg = c0g + n * 16 + (lane & 15);
#pragma unroll
                for (int q = 0; q < 4; ++q) {
                    int rloc = ai * 16 + (lane >> 4) * 4 + q;
                    int r = r0g + rloc;
                    size_t idx = (size_t)r * C_ + cg;
                    float P = acc[ai][n][q];
                    float val = alpha * P;
                    if (r == cg) val += diagv;
                    if (e1h) val += beta * (bf2f(e1h[idx]) + bf2f(e1l[idx]));
                    if (e2h) val += gamma * (bf2f(e2h[idx]) + bf2f(e2l[idx]));
                    if (o1h) {
                        u16 h = f2bf(val);
                        o1h[idx] = h;
                        o1l[idx] = f2bf(val - bf2f(h));
                    }
                    if (o2h) {
                        float v2 = alpha2 * P;
                        if (r == cg) v2 += diag2;
                        u16 h2 = f2bf(v2);
                        o2h[idx] = h2;
                        o2l[idx] = f2bf(v2 - bf2f(h2));
                    }
                    if (O1th) scr[(rloc - p * 32) * 68 + n * 16 + (lane & 15)] = val;
                }
            }
        }
        if (O1th) {
            u16* o1th = O1th + eoff;
            u16* o1tl = O1tl + eoff;
#pragma unroll
            for (int g = 0; g < 4; ++g) {
                u32 hw[4], lw[4];
#pragma unroll
                for (int e2 = 0; e2 < 4; ++e2) {
                    float v0 = scr[(g * 8 + 2 * e2) * 68 + lane];
                    float v1 = scr[(g * 8 + 2 * e2 + 1) * 68 + lane];
                    u16 h0 = f2bf(v0), h1 = f2bf(v1);
                    u16 l0 = f2bf(v0 - bf2f(h0)), l1 = f2bf(v1 - bf2f(h1));
                    hw[e2] = (u32)h0 | ((u32)h1 << 16);
                    lw[e2] = (u32)l0 | ((u32)l1 << 16);
                }
                size_t tidx = (size_t)(c0g + lane) * C_ + r0g + p * 32 + g * 8;
                uint4 ph; ph.x = hw[0]; ph.y = hw[1]; ph.z = hw[2]; ph.w = hw[3];
                uint4 pl; pl.x = lw[0]; pl.y = lw[1]; pl.z = lw[2]; pl.w = lw[3];
                *(uint4*)&o1th[tidx] = ph;
                *(uint4*)&o1tl[tidx] = pl;
            }
        }
    }
}

// ---------------------------------------------------------------- host
static inline void launch_gemm(hipStream_t st, int bc,
    const u16* Ah, const u16* Al, size_t sA, int lda, int K,
    const u16* Bh, const u16* Bl, size_t sB,
    float alpha, float diagv,
    const u16* E1h, const u16* E1l, float beta,
    const u16* E2h, const u16* E2l, float gamma,
    u16* O1h, u16* O1l, u16* O1th, u16* O1tl,
    float alpha2, float diag2, u16* O2h, u16* O2l)
{
    gemm_ns<<<dim3(4, 4, bc), 256, 0, st>>>(Ah, Al, Bh, Bl, K, lda, sA, sB,
        alpha, diagv, E1h, E1l, beta, E2h, E2l, gamma,
        O1h, O1l, O1th, O1tl, alpha2, diag2, O2h, O2l);
}

extern "C" void kernel_launch(void* const* d_in, const int* in_sizes, int n_in,
                              void* d_out, int out_size, void* d_ws, size_t ws_size,
                              hipStream_t stream) {
    const float* X = (const float*)d_in[0];
    float* out = (float*)d_out;
    float* hdr = (float*)d_ws;

    float* mu   = hdr;
    float* ssq  = mu + (size_t)B_ * D_;
    float* rfro = ssq + B_;
    float* avec = rfro + B_;
    float* w2v  = avec + (size_t)B_ * C_;
    float* svec = w2v + (size_t)B_ * C_;
    float* ycov = svec + (size_t)B_ * D_;
    size_t hdrBytes = (size_t)((char*)(ycov + (size_t)B_ * D_) - (char*)hdr);
    size_t matsOff = (hdrBytes + 255) & ~(size_t)255;

    size_t perBatch = (2 * WN_ + 28 * NN_) * 2;   // bytes
    size_t avail = ws_size > matsOff ? ws_size - matsOff : 0;
    int NB = (int)(avail / perBatch);
    if (NB < 1) NB = 1;
    if (NB > B_) NB = B_;

    u16* q = (u16*)((char*)d_ws + matsOff);
    u16* Wh = q; q += (size_t)NB * WN_;
    u16* Wl = q; q += (size_t)NB * WN_;
    u16* Gh = q; q += (size_t)NB * NN_;
    u16* Gl = q; q += (size_t)NB * NN_;
    u16* ys[2][4]; u16* zs[2][4];
    for (int s = 0; s < 2; ++s)
        for (int a = 0; a < 4; ++a) { ys[s][a] = q; q += (size_t)NB * NN_; }
    for (int s = 0; s < 2; ++s)
        for (int a = 0; a < 4; ++a) { zs[s][a] = q; q += (size_t)NB * NN_; }
    u16* th  = q; q += (size_t)NB * NN_;
    u16* tl  = q; q += (size_t)NB * NN_;
    u16* tth = q; q += (size_t)NB * NN_;
    u16* ttl = q; q += (size_t)NB * NN_;
    u16* uth = q; q += (size_t)NB * NN_;
    u16* utl = q; q += (size_t)NB * NN_;
    u16* vh  = q; q += (size_t)NB * NN_;
    u16* vl  = q; q += (size_t)NB * NN_;
    u16* vth = q; q += (size_t)NB * NN_;
    u16* vtl = q; q += (size_t)NB * NN_;

    zero_kernel<<<1, 64, 0, stream>>>(ssq, B_);
    mu_kernel<<<dim3((D_ + 255) / 256, B_), 256, 0, stream>>>(X, mu, ssq);
    rfro_kernel<<<B_, 256, 0, stream>>>(mu, ssq, rfro);

    for (int b0 = 0; b0 < B_; b0 += NB) {
        int bc = (B_ - b0 < NB) ? (B_ - b0) : NB;

        size_t wbTotal = (size_t)bc * C_ * (DP_ / 8);
        wbuild_kernel<<<(unsigned)((wbTotal + 255) / 256), 256, 0, stream>>>(X, mu, rfro, Wh, Wl, b0, bc);
        size_t ziTotal = (size_t)bc * NN_;
        z0init_kernel<<<(unsigned)((ziTotal + 255) / 256), 256, 0, stream>>>(zs[0][0], zs[0][1], zs[0][2], zs[0][3], bc);
        arowsum_kernel<<<dim3(C_, bc), 128, 0, stream>>>(Wh, Wl, avec, b0);

        // SYRK: G = W W^T ; second output y0 = 1.5 I - 0.5 G (y0^T == y0 at fp32 level)
        launch_gemm(stream, bc, Wh, Wl, WN_, DP_, DP_, Wh, Wl, WN_,
                    1.f, 0.f, 0, 0, 0.f, 0, 0, 0.f,
                    Gh, Gl, 0, 0, -0.5f, 1.5f, ys[0][0], ys[0][1]);

        u16* cy[4] = { ys[0][0], ys[0][1], ys[0][0], ys[0][1] };  // y0: tr aliases row
        u16* cz[4] = { zs[0][0], zs[0][1], zs[0][2], zs[0][3] };
        int ynext = 1, znext = 1;
        float c = 1.5f;

        for (int it = 0; it < 4; ++it) {
            bool last = (it == 3);
            // P1: u = G @ y   (store transposed only)
            launch_gemm(stream, bc, Gh, Gl, NN_, C_, C_, cy[2], cy[3], NN_,
                        1.f, 0.f, 0, 0, 0.f, 0, 0, 0.f,
                        0, 0, uth, utl, 0.f, 0.f, 0, 0);
            // P2: t = -0.5*(z@u) - 0.5*c*y
            launch_gemm(stream, bc, cz[0], cz[1], NN_, C_, C_, uth, utl, NN_,
                        -0.5f, 0.f, cy[0], cy[1], -0.5f * c, 0, 0, 0.f,
                        th, tl, tth, ttl, 0.f, 0.f, 0, 0);
            // P3: v = G @ t   (row copy not needed on last iter)
            launch_gemm(stream, bc, Gh, Gl, NN_, C_, C_, tth, ttl, NN_,
                        1.f, 0.f, 0, 0, 0.f, 0, 0, 0.f,
                        last ? 0 : vh, last ? 0 : vl, vth, vtl, 0.f, 0.f, 0, 0);
            // P4: y' = 1.5 y + y@v
            launch_gemm(stream, bc, cy[0], cy[1], NN_, C_, C_, vth, vtl, NN_,
                        1.f, 0.f, cy[0], cy[1], 1.5f, 0, 0, 0.f,
                        ys[ynext][0], ys[ynext][1],
                        last ? 0 : ys[ynext][2], last ? 0 : ys[ynext][3],
                        0.f, 0.f, 0, 0);
            cy[0] = ys[ynext][0]; cy[1] = ys[ynext][1];
            cy[2] = ys[ynext][2]; cy[3] = ys[ynext][3];
            ynext = 1 - ynext;
            if (!last) {
                // P5: z' = 1.5 z + c t + v@z
                launch_gemm(stream, bc, vh, vl, NN_, C_, C_, cz[2], cz[3], NN_,
                            1.f, 0.f, cz[0], cz[1], 1.5f, th, tl, c,
                            zs[znext][0], zs[znext][1], zs[znext][2], zs[znext][3],
                            0.f, 0.f, 0, 0);
                cz[0] = zs[znext][0]; cz[1] = zs[znext][1];
                cz[2] = zs[znext][2]; cz[3] = zs[znext][3];
                znext = 1 - znext;
                c *= 1.5f;
            }
        }

        w2_kernel<<<dim3(2, bc), 256, 0, stream>>>(cy[0], cy[1], avec, w2v, b0);
        svec_kernel<<<dim3(4, bc), 256, 0, stream>>>(w2v, Wh, Wl, svec, b0);
        minmax_kernel<<<bc, 256, 0, stream>>>(svec, ycov, b0);
    }

    size_t n4 = ((size_t)B_ * C_ * D_) / 4;
    scale_kernel<<<(unsigned)((n4 + 255) / 256), 256, 0, stream>>>(X, ycov, out);
}

// Round 3
// 2434.478 us; speedup vs baseline: 5.3497x; 1.6284x over previous
//
#include <hip/hip_runtime.h>

// SOSA forward — round 3: symmetric Gram-domain NS + 2-phase pipelined split-3 MFMA.
// All NS iterates are polynomials in symmetric G=WW^T -> symmetric -> B^T == B:
// no transposed copies, no epilogue transpose. NB=32 batch groups keep the
// ~290MB working set ~L3-resident; grid 512 blocks = 2 blocks/CU, 2 waves/SIMD.
// GEMM: 128^2 tile, 4 waves (64x64 each), BK=32, double-buffered LDS (72KB),
// reg-staged 2-phase pipeline (stage t+1 issued before MFMA of t, 1 barrier/step).

typedef unsigned short u16;
typedef unsigned int u32;
typedef short bf16x8 __attribute__((ext_vector_type(8)));
typedef float f32x4 __attribute__((ext_vector_type(4)));

#define B_  64
#define C_  512
#define D_  784
#define DP_ 800
#define NN_ ((size_t)C_ * C_)   // 262144
#define WN_ ((size_t)C_ * DP_)  // 409600
#define NBMAX 32

__device__ inline u16 f2bf(float f) {
    u32 u = __builtin_bit_cast(u32, f);
    u += 0x7fffu + ((u >> 16) & 1u);
    return (u16)(u >> 16);
}
__device__ inline float bf2f(u16 h) {
    u32 u = ((u32)h) << 16;
    return __builtin_bit_cast(float, u);
}

// ---------------------------------------------------------------- small ops
__global__ __launch_bounds__(64) void zero_kernel(float* __restrict__ p, int n) {
    int i = blockIdx.x * 64 + threadIdx.x;
    if (i < n) p[i] = 0.f;
}

__global__ __launch_bounds__(256) void mu_kernel(const float* __restrict__ X,
                                                 float* __restrict__ mu,
                                                 float* __restrict__ ssq) {
    int b = blockIdx.y;
    int i = blockIdx.x * 256 + threadIdx.x;
    float s = 0.f, q = 0.f;
    if (i < D_) {
        const float* xb = X + (size_t)b * C_ * D_ + i;
        for (int c = 0; c < C_; ++c) { float v = xb[(size_t)c * D_]; s += v; q += v * v; }
        mu[b * D_ + i] = s * (1.f / C_);
    }
    __shared__ float red[256];
    red[threadIdx.x] = q;
    __syncthreads();
    for (int off = 128; off > 0; off >>= 1) {
        if (threadIdx.x < off) red[threadIdx.x] += red[threadIdx.x + off];
        __syncthreads();
    }
    if (threadIdx.x == 0) atomicAdd(&ssq[b], red[0]);
}

__global__ __launch_bounds__(256) void rfro_kernel(const float* __restrict__ mu,
                                                   const float* __restrict__ ssq,
                                                   float* __restrict__ rfro) {
    int b = blockIdx.x;
    float q = 0.f;
    for (int i = threadIdx.x; i < D_; i += 256) { float m = mu[b * D_ + i]; q += m * m; }
    __shared__ float red[256];
    red[threadIdx.x] = q;
    __syncthreads();
    for (int off = 128; off > 0; off >>= 1) {
        if (threadIdx.x < off) red[threadIdx.x] += red[threadIdx.x + off];
        __syncthreads();
    }
    if (threadIdx.x == 0) rfro[b] = rsqrtf(ssq[b] - (float)C_ * red[0]);
}

// W = (X - mu) * rfro, split hi/lo bf16, cols 784..799 zero.
__global__ __launch_bounds__(256) void wbuild_kernel(const float* __restrict__ X,
                                                     const float* __restrict__ mu,
                                                     const float* __restrict__ rfro,
                                                     u16* __restrict__ Wh, u16* __restrict__ Wl,
                                                     int b0, int bc) {
    size_t idx = (size_t)blockIdx.x * 256 + threadIdx.x;
    size_t total = (size_t)bc * C_ * (DP_ / 8);
    if (idx >= total) return;
    int ch = (int)(idx % (DP_ / 8));
    size_t rest = idx / (DP_ / 8);
    int c = (int)(rest % C_);
    int bz = (int)(rest / C_);
    int b = b0 + bz;
    int i0 = ch * 8;
    u32 hw[4] = {0, 0, 0, 0}, lw[4] = {0, 0, 0, 0};
    if (i0 < D_) {
        float rf = rfro[b];
        const float* xr = X + ((size_t)b * C_ + c) * D_ + i0;
        const float* mr = mu + (size_t)b * D_ + i0;
#pragma unroll
        for (int e2 = 0; e2 < 4; ++e2) {
            float v0 = (xr[2 * e2] - mr[2 * e2]) * rf;
            float v1 = (xr[2 * e2 + 1] - mr[2 * e2 + 1]) * rf;
            u16 h0 = f2bf(v0), h1 = f2bf(v1);
            u16 l0 = f2bf(v0 - bf2f(h0)), l1 = f2bf(v1 - bf2f(h1));
            hw[e2] = (u32)h0 | ((u32)h1 << 16);
            lw[e2] = (u32)l0 | ((u32)l1 << 16);
        }
    }
    size_t o = ((size_t)bz * C_ + c) * DP_ + i0;
    uint4 ph; ph.x = hw[0]; ph.y = hw[1]; ph.z = hw[2]; ph.w = hw[3];
    uint4 pl; pl.x = lw[0]; pl.y = lw[1]; pl.z = lw[2]; pl.w = lw[3];
    *(uint4*)&Wh[o] = ph;
    *(uint4*)&Wl[o] = pl;
}

// z0 = -0.5 I, vectorized by 8
__global__ __launch_bounds__(256) void z0init_kernel(u16* __restrict__ zh, u16* __restrict__ zl,
                                                     int bc) {
    size_t i8 = (size_t)blockIdx.x * 256 + threadIdx.x;
    size_t tot = (size_t)bc * NN_ / 8;
    if (i8 >= tot) return;
    size_t e0 = i8 * 8;
    int r = (int)((e0 >> 9) & 511);
    int c0 = (int)(e0 & 511);
    u32 w[4] = {0, 0, 0, 0};
    int dj = r - c0;
    if (dj >= 0 && dj < 8) w[dj >> 1] |= ((u32)0xBF00u) << ((dj & 1) * 16);
    uint4 ph; ph.x = w[0]; ph.y = w[1]; ph.z = w[2]; ph.w = w[3];
    uint4 zzero; zzero.x = 0; zzero.y = 0; zzero.z = 0; zzero.w = 0;
    *(uint4*)&zh[e0] = ph;
    *(uint4*)&zl[e0] = zzero;
}

// avec[b,c] = (1/d) sum_i W[c,i]
__global__ __launch_bounds__(128) void arowsum_kernel(const u16* __restrict__ Wh,
                                                      const u16* __restrict__ Wl,
                                                      float* __restrict__ avec, int b0) {
    int c = blockIdx.x, bz = blockIdx.y;
    const u16* wh = Wh + ((size_t)bz * C_ + c) * DP_;
    const u16* wl = Wl + ((size_t)bz * C_ + c) * DP_;
    float s = 0.f;
    for (int i = threadIdx.x; i < DP_; i += 128) s += bf2f(wh[i]) + bf2f(wl[i]);
    __shared__ float red[128];
    red[threadIdx.x] = s;
    __syncthreads();
    for (int off = 64; off > 0; off >>= 1) {
        if (threadIdx.x < off) red[threadIdx.x] += red[threadIdx.x + off];
        __syncthreads();
    }
    if (threadIdx.x == 0) avec[(size_t)(b0 + bz) * C_ + c] = red[0] * (1.f / D_);
}

// r1[b,c] = sum_j y[c,j]*avec[b,j]
__global__ __launch_bounds__(128) void ra_kernel(const u16* __restrict__ yh,
                                                 const u16* __restrict__ yl,
                                                 const float* __restrict__ avec,
                                                 float* __restrict__ r1, int b0) {
    int c = blockIdx.x, bz = blockIdx.y;
    int b = b0 + bz;
    const u16* ph = yh + (size_t)bz * NN_ + (size_t)c * C_;
    const u16* pl = yl + (size_t)bz * NN_ + (size_t)c * C_;
    const float* av = avec + (size_t)b * C_;
    float s = 0.f;
    for (int j = threadIdx.x; j < C_; j += 128) s += (bf2f(ph[j]) + bf2f(pl[j])) * av[j];
    __shared__ float red[128];
    red[threadIdx.x] = s;
    __syncthreads();
    for (int off = 64; off > 0; off >>= 1) {
        if (threadIdx.x < off) red[threadIdx.x] += red[threadIdx.x + off];
        __syncthreads();
    }
    if (threadIdx.x == 0) r1[(size_t)b * C_ + c] = red[0];
}

// w2[b,j] = 1.5*r1[b,j] + sum_c v[j,c]*r1[b,c]
__global__ __launch_bounds__(128) void w2_kernel(const u16* __restrict__ vh,
                                                 const u16* __restrict__ vl,
                                                 const float* __restrict__ r1,
                                                 float* __restrict__ w2, int b0) {
    int j = blockIdx.x, bz = blockIdx.y;
    int b = b0 + bz;
    const u16* ph = vh + (size_t)bz * NN_ + (size_t)j * C_;
    const u16* pl = vl + (size_t)bz * NN_ + (size_t)j * C_;
    const float* r = r1 + (size_t)b * C_;
    float s = 0.f;
    for (int c = threadIdx.x; c < C_; c += 128) s += (bf2f(ph[c]) + bf2f(pl[c])) * r[c];
    __shared__ float red[128];
    red[threadIdx.x] = s;
    __syncthreads();
    for (int off = 64; off > 0; off >>= 1) {
        if (threadIdx.x < off) red[threadIdx.x] += red[threadIdx.x + off];
        __syncthreads();
    }
    if (threadIdx.x == 0) w2[(size_t)b * C_ + j] = 1.5f * r[j] + red[0];
}

// svec[b,j] = sum_c w2[b,c]*W[c,j]
__global__ __launch_bounds__(256) void svec_kernel(const float* __restrict__ w2,
                                                   const u16* __restrict__ Wh,
                                                   const u16* __restrict__ Wl,
                                                   float* __restrict__ svec, int b0) {
    int bz = blockIdx.y;
    int j = blockIdx.x * 256 + threadIdx.x;
    if (j >= D_) return;
    const u16* wh = Wh + (size_t)bz * WN_;
    const u16* wl = Wl + (size_t)bz * WN_;
    const float* w = w2 + (size_t)(b0 + bz) * C_;
    float s = 0.f;
    for (int c = 0; c < C_; ++c) s += w[c] * (bf2f(wh[(size_t)c * DP_ + j]) + bf2f(wl[(size_t)c * DP_ + j]));
    svec[(size_t)(b0 + bz) * D_ + j] = s;
}

__global__ __launch_bounds__(256) void minmax_kernel(const float* __restrict__ s,
                                                     float* __restrict__ ycov, int b0) {
    int b = b0 + blockIdx.x;
    const float* sb = s + (size_t)b * D_;
    float mn = 1e30f, mx = -1e30f;
    for (int i = threadIdx.x; i < D_; i += 256) {
        float v = sb[i];
        mn = fminf(mn, v);
        mx = fmaxf(mx, v);
    }
    __shared__ float rmn[256], rmx[256];
    rmn[threadIdx.x] = mn;
    rmx[threadIdx.x] = mx;
    __syncthreads();
    for (int off = 128; off > 0; off >>= 1) {
        if (threadIdx.x < off) {
            rmn[threadIdx.x] = fminf(rmn[threadIdx.x], rmn[threadIdx.x + off]);
            rmx[threadIdx.x] = fmaxf(rmx[threadIdx.x], rmx[threadIdx.x + off]);
        }
        __syncthreads();
    }
    float gmn = rmn[0], gmx = rmx[0];
    float inv = 1.f / (gmx - gmn);
    for (int i = threadIdx.x; i < D_; i += 256)
        ycov[(size_t)b * D_ + i] = (sb[i] - gmn) * inv;
}

__global__ __launch_bounds__(256) void scale_kernel(const float* __restrict__ X,
                                                    const float* __restrict__ ycov,
                                                    float* __restrict__ out) {
    size_t idx = (size_t)blockIdx.x * 256 + threadIdx.x;
    size_t n = idx * 4;
    if (n >= (size_t)B_ * C_ * D_) return;
    int b = (int)(n / ((size_t)C_ * D_));
    int i = (int)(n % D_);
    float4 x4 = *(const float4*)(X + n);
    float4 y4 = *(const float4*)(ycov + (size_t)b * D_ + i);
    float4 o;
    o.x = x4.x * y4.x; o.y = x4.y * y4.y; o.z = x4.z * y4.z; o.w = x4.w * y4.w;
    *(float4*)(out + n) = o;
}

// ---------------------------------------------------------------- MFMA GEMM
// C(512x512)[bz] = alpha*(A@B) + diagv*I + beta*E1 + gamma*E2 (B symmetric ->
// staged by rows). Split-3 bf16: P = Ah@Bh + Ah@Bl + Al@Bh, fp32 accum.
// 128^2 tile, 4 waves (64x64), BK=32, double-buffered LDS, 2-phase pipeline.
__global__ __launch_bounds__(256, 2) void gemm_ns(
    const u16* __restrict__ Ah, const u16* __restrict__ Al, int ldA, size_t sA,
    const u16* __restrict__ Bh, const u16* __restrict__ Bl, int ldB, size_t sB,
    int K,
    float alpha, float diagv,
    const u16* __restrict__ E1h, const u16* __restrict__ E1l, float beta,
    const u16* __restrict__ E2h, const u16* __restrict__ E2l, float gamma,
    u16* __restrict__ O1h, u16* __restrict__ O1l,
    float alpha2, float diag2,
    u16* __restrict__ O2h, u16* __restrict__ O2l)
{
    __shared__ u16 lds[2][4][128][36];   // dbuf x {Ah,Al,Bh,Bl} x rows x (32+4 pad)
    int bz = blockIdx.z;
    int t = threadIdx.x;
    int lane = t & 63, wid = t >> 6;
    int wr = wid >> 1, wc = wid & 1;
    int row0 = blockIdx.y * 128, col0 = blockIdx.x * 128;
    const u16* pA0 = Ah + (size_t)bz * sA;
    const u16* pA1 = Al + (size_t)bz * sA;
    const u16* pB0 = Bh + (size_t)bz * sB;
    const u16* pB1 = Bl + (size_t)bz * sB;
    int lr = t >> 2, lkc = (t & 3) * 8;   // loader: rows lr, lr+64; 8-elem k-chunk
    f32x4 acc[4][4] = {};
    uint4 rg0, rg1, rg2, rg3, rg4, rg5, rg6, rg7;

#define STAGE(k0) do { \
    rg0 = *(const uint4*)&pA0[(size_t)(row0 + lr) * ldA + (k0) + lkc]; \
    rg1 = *(const uint4*)&pA0[(size_t)(row0 + lr + 64) * ldA + (k0) + lkc]; \
    rg2 = *(const uint4*)&pA1[(size_t)(row0 + lr) * ldA + (k0) + lkc]; \
    rg3 = *(const uint4*)&pA1[(size_t)(row0 + lr + 64) * ldA + (k0) + lkc]; \
    rg4 = *(const uint4*)&pB0[(size_t)(col0 + lr) * ldB + (k0) + lkc]; \
    rg5 = *(const uint4*)&pB0[(size_t)(col0 + lr + 64) * ldB + (k0) + lkc]; \
    rg6 = *(const uint4*)&pB1[(size_t)(col0 + lr) * ldB + (k0) + lkc]; \
    rg7 = *(const uint4*)&pB1[(size_t)(col0 + lr + 64) * ldB + (k0) + lkc]; \
} while (0)
#define WLDS(bf) do { \
    *(uint4*)&lds[bf][0][lr][lkc] = rg0; \
    *(uint4*)&lds[bf][0][lr + 64][lkc] = rg1; \
    *(uint4*)&lds[bf][1][lr][lkc] = rg2; \
    *(uint4*)&lds[bf][1][lr + 64][lkc] = rg3; \
    *(uint4*)&lds[bf][2][lr][lkc] = rg4; \
    *(uint4*)&lds[bf][2][lr + 64][lkc] = rg5; \
    *(uint4*)&lds[bf][3][lr][lkc] = rg6; \
    *(uint4*)&lds[bf][3][lr + 64][lkc] = rg7; \
} while (0)

    STAGE(0);
    WLDS(0);
    __syncthreads();

    int nst = K >> 5;
    for (int s = 0; s < nst; ++s) {
        int cur = s & 1;
        bool more = (s + 1 < nst);
        if (more) STAGE((s + 1) * 32);        // issue next-tile loads early
        int koff = (lane >> 4) * 8;
        int fr = lane & 15;
        bf16x8 bhf[4], blf[4];
#pragma unroll
        for (int n = 0; n < 4; ++n) {
            int rB = wc * 64 + n * 16 + fr;
            bhf[n] = *(const bf16x8*)&lds[cur][2][rB][koff];
            blf[n] = *(const bf16x8*)&lds[cur][3][rB][koff];
        }
#pragma unroll
        for (int m = 0; m < 4; ++m) {
            int rA = wr * 64 + m * 16 + fr;
            bf16x8 ah = *(const bf16x8*)&lds[cur][0][rA][koff];
            bf16x8 al = *(const bf16x8*)&lds[cur][1][rA][koff];
#pragma unroll
            for (int n = 0; n < 4; ++n) {
                acc[m][n] = __builtin_amdgcn_mfma_f32_16x16x32_bf16(ah, bhf[n], acc[m][n], 0, 0, 0);
                acc[m][n] = __builtin_amdgcn_mfma_f32_16x16x32_bf16(ah, blf[n], acc[m][n], 0, 0, 0);
                acc[m][n] = __builtin_amdgcn_mfma_f32_16x16x32_bf16(al, bhf[n], acc[m][n], 0, 0, 0);
            }
        }
        if (more) {
            WLDS(cur ^ 1);                    // compiler waits vmcnt for rg*
            __syncthreads();
        }
    }
#undef STAGE
#undef WLDS

    // epilogue: row-major writes only (outputs symmetric)
    size_t eoff = (size_t)bz * NN_;
    const u16* e1h = E1h ? E1h + eoff : (const u16*)0;
    const u16* e1l = E1l ? E1l + eoff : (const u16*)0;
    const u16* e2h = E2h ? E2h + eoff : (const u16*)0;
    const u16* e2l = E2l ? E2l + eoff : (const u16*)0;
    u16* o1h = O1h + eoff;
    u16* o1l = O1l + eoff;
    u16* o2h = O2h ? O2h + eoff : (u16*)0;
    u16* o2l = O2l ? O2l + eoff : (u16*)0;
    int rBase = row0 + wr * 64 + (lane >> 4) * 4;
    int cBase = col0 + wc * 64 + (lane & 15);
#pragma unroll
    for (int m = 0; m < 4; ++m) {
#pragma unroll
        for (int n = 0; n < 4; ++n) {
            int cg = cBase + n * 16;
#pragma unroll
            for (int q = 0; q < 4; ++q) {
                int r = rBase + m * 16 + q;
                size_t idx = ((size_t)r << 9) + cg;
                float P = acc[m][n][q];
                float val = alpha * P;
                if (r == cg) val += diagv;
                if (e1h) val += beta * (bf2f(e1h[idx]) + bf2f(e1l[idx]));
                if (e2h) val += gamma * (bf2f(e2h[idx]) + bf2f(e2l[idx]));
                u16 h = f2bf(val);
                o1h[idx] = h;
                o1l[idx] = f2bf(val - bf2f(h));
                if (o2h) {
                    float v2 = alpha2 * P;
                    if (r == cg) v2 += diag2;
                    u16 h2 = f2bf(v2);
                    o2h[idx] = h2;
                    o2l[idx] = f2bf(v2 - bf2f(h2));
                }
            }
        }
    }
}

// ---------------------------------------------------------------- host
static inline void launch_gemm(hipStream_t st, int bc,
    const u16* Ah, const u16* Al, int ldA, size_t sA,
    const u16* Bh, const u16* Bl, int ldB, size_t sB, int K,
    float alpha, float diagv,
    const u16* E1h, const u16* E1l, float beta,
    const u16* E2h, const u16* E2l, float gamma,
    u16* O1h, u16* O1l,
    float alpha2, float diag2, u16* O2h, u16* O2l)
{
    gemm_ns<<<dim3(4, 4, bc), 256, 0, st>>>(Ah, Al, ldA, sA, Bh, Bl, ldB, sB, K,
        alpha, diagv, E1h, E1l, beta, E2h, E2l, gamma,
        O1h, O1l, alpha2, diag2, O2h, O2l);
}

extern "C" void kernel_launch(void* const* d_in, const int* in_sizes, int n_in,
                              void* d_out, int out_size, void* d_ws, size_t ws_size,
                              hipStream_t stream) {
    const float* X = (const float*)d_in[0];
    float* out = (float*)d_out;
    float* hdr = (float*)d_ws;

    float* mu   = hdr;
    float* ssq  = mu + (size_t)B_ * D_;
    float* rfro = ssq + B_;
    float* avec = rfro + B_;
    float* r1v  = avec + (size_t)B_ * C_;
    float* w2v  = r1v + (size_t)B_ * C_;
    float* svec = w2v + (size_t)B_ * C_;
    float* ycov = svec + (size_t)B_ * D_;
    size_t hdrBytes = (size_t)((char*)(ycov + (size_t)B_ * D_) - (char*)hdr);
    size_t matsOff = (hdrBytes + 255) & ~(size_t)255;

    const size_t perBatch = (2 * WN_ + 16 * NN_) * 2;   // bytes (~9.6 MB)
    size_t avail = ws_size > matsOff ? ws_size - matsOff : 0;
    int NB = (int)(avail / perBatch);
    if (NB < 1) NB = 1;
    if (NB > NBMAX) NB = NBMAX;

    u16* q = (u16*)((char*)d_ws + matsOff);
    u16* Wh = q; q += (size_t)NB * WN_;
    u16* Wl = q; q += (size_t)NB * WN_;
    u16* Gh = q; q += (size_t)NB * NN_;
    u16* Gl = q; q += (size_t)NB * NN_;
    u16* ybuf[2][2]; u16* zbuf[2][2];
    for (int s = 0; s < 2; ++s)
        for (int a = 0; a < 2; ++a) { ybuf[s][a] = q; q += (size_t)NB * NN_; }
    for (int s = 0; s < 2; ++s)
        for (int a = 0; a < 2; ++a) { zbuf[s][a] = q; q += (size_t)NB * NN_; }
    u16* th = q; q += (size_t)NB * NN_;
    u16* tl = q; q += (size_t)NB * NN_;
    u16* uh = q; q += (size_t)NB * NN_;
    u16* ul = q; q += (size_t)NB * NN_;
    u16* vh = q; q += (size_t)NB * NN_;
    u16* vl = q; q += (size_t)NB * NN_;

    zero_kernel<<<1, 64, 0, stream>>>(ssq, B_);
    mu_kernel<<<dim3((D_ + 255) / 256, B_), 256, 0, stream>>>(X, mu, ssq);
    rfro_kernel<<<B_, 256, 0, stream>>>(mu, ssq, rfro);

    for (int b0 = 0; b0 < B_; b0 += NB) {
        int bc = (B_ - b0 < NB) ? (B_ - b0) : NB;

        size_t wbTotal = (size_t)bc * C_ * (DP_ / 8);
        wbuild_kernel<<<(unsigned)((wbTotal + 255) / 256), 256, 0, stream>>>(X, mu, rfro, Wh, Wl, b0, bc);
        size_t ziTotal = (size_t)bc * NN_ / 8;
        z0init_kernel<<<(unsigned)((ziTotal + 255) / 256), 256, 0, stream>>>(zbuf[0][0], zbuf[0][1], bc);
        arowsum_kernel<<<dim3(C_, bc), 128, 0, stream>>>(Wh, Wl, avec, b0);

        // SYRK: G = W W^T ; second output y0 = 1.5 I - 0.5 G
        launch_gemm(stream, bc, Wh, Wl, DP_, WN_, Wh, Wl, DP_, WN_, DP_,
                    1.f, 0.f, 0, 0, 0.f, 0, 0, 0.f,
                    Gh, Gl, -0.5f, 1.5f, ybuf[0][0], ybuf[0][1]);

        u16* cy[2] = { ybuf[0][0], ybuf[0][1] };
        u16* cz[2] = { zbuf[0][0], zbuf[0][1] };
        int ynext = 1, znext = 1;
        float c = 1.5f;

        for (int it = 0; it < 4; ++it) {
            bool last = (it == 3);
            // P1: u = G @ y
            launch_gemm(stream, bc, Gh, Gl, C_, NN_, cy[0], cy[1], C_, NN_, C_,
                        1.f, 0.f, 0, 0, 0.f, 0, 0, 0.f,
                        uh, ul, 0.f, 0.f, 0, 0);
            // P2: t = -0.5*(z@u) - 0.5*c*y
            launch_gemm(stream, bc, cz[0], cz[1], C_, NN_, uh, ul, C_, NN_, C_,
                        -0.5f, 0.f, cy[0], cy[1], -0.5f * c, 0, 0, 0.f,
                        th, tl, 0.f, 0.f, 0, 0);
            // P3: v = G @ t
            launch_gemm(stream, bc, Gh, Gl, C_, NN_, th, tl, C_, NN_, C_,
                        1.f, 0.f, 0, 0, 0.f, 0, 0, 0.f,
                        vh, vl, 0.f, 0.f, 0, 0);
            if (!last) {
                // P4: y' = 1.5 y + y@v
                launch_gemm(stream, bc, cy[0], cy[1], C_, NN_, vh, vl, C_, NN_, C_,
                            1.f, 0.f, cy[0], cy[1], 1.5f, 0, 0, 0.f,
                            ybuf[ynext][0], ybuf[ynext][1], 0.f, 0.f, 0, 0);
                // P5: z' = 1.5 z + c t + v@z
                launch_gemm(stream, bc, vh, vl, C_, NN_, cz[0], cz[1], C_, NN_, C_,
                            1.f, 0.f, cz[0], cz[1], 1.5f, th, tl, c,
                            zbuf[znext][0], zbuf[znext][1], 0.f, 0.f, 0, 0);
                cy[0] = ybuf[ynext][0]; cy[1] = ybuf[ynext][1]; ynext = 1 - ynext;
                cz[0] = zbuf[znext][0]; cz[1] = zbuf[znext][1]; znext = 1 - znext;
                c *= 1.5f;
            }
        }

        // w2 = a^T yf = 1.5*(y a) + v*(y a)   (replaces final P4 GEMM)
        ra_kernel<<<dim3(C_, bc), 128, 0, stream>>>(cy[0], cy[1], avec, r1v, b0);
        w2_kernel<<<dim3(C_, bc), 128, 0, stream>>>(vh, vl, r1v, w2v, b0);
        svec_kernel<<<dim3(4, bc), 256, 0, stream>>>(w2v, Wh, Wl, svec, b0);
        minmax_kernel<<<bc, 256, 0, stream>>>(svec, ycov, b0);
    }

    size_t n4 = ((size_t)B_ * C_ * D_) / 4;
    scale_kernel<<<(unsigned)((n4 + 255) / 256), 256, 0, stream>>>(X, ycov, out);
}